// Round 12
// baseline (200.430 us; speedup 1.0000x reference)
//
#include <hip/hip_runtime.h>
#include <hip/hip_bf16.h>

typedef __hip_bfloat16 bf16;
typedef __attribute__((ext_vector_type(8))) short bf16x8;
typedef __attribute__((ext_vector_type(4))) float floatx4;

#define NB 16
#define NC 256
#define NPIX 4096
#define NHID 128
#define NH 4
#define ND 32
#define NMEM 4
#define QSCALE 0.17677669529663687f  // 32^-0.5

// ---------------- kW: pack wqkv*g -> bf16 in MFMA A-frag tile order.
// Also zeroes the ctxu/zacc accumulators (adjacent in ws).
__launch_bounds__(256)
__global__ void kW(const float* __restrict__ wqkv, const float* __restrict__ g,
                   bf16* __restrict__ wgpack, float* __restrict__ zbase){
  const int u = blockIdx.x*256 + threadIdx.x;     // 12288 chunks
  for (int z = u; z < 65536 + 2048; z += 48*256) zbase[z] = 0.f;
  const int s = u / 1536;
  const int r = u - s*1536;
  const int tile = r >> 6, l = r & 63;
  const int row = tile*16 + (l & 15);
  const int kb  = s*32 + (l >> 4)*8;
  const float* wp = wqkv + (size_t)row*NC + kb;
  floatx4 w0 = *(const floatx4*)wp;
  floatx4 w1 = *(const floatx4*)(wp + 4);
  floatx4 g0 = *(const floatx4*)(g + kb);
  floatx4 g1 = *(const floatx4*)(g + kb + 4);
  alignas(16) bf16 tmp[8];
  #pragma unroll
  for (int i = 0; i < 4; ++i){
    tmp[i]   = __float2bfloat16(w0[i]*g0[i]);
    tmp[4+i] = __float2bfloat16(w1[i]*g1[i]);
  }
  *(uint4*)(wgpack + (size_t)u*8) = *(const uint4*)tmp;
}

// ---------------- kT (new): x [b][ch][px] f32 -> x^T [b][px][ch] bf16, plus
// per-px ssq -> sLg = 16/max(sqrt(ssq),eps). Pure bandwidth pass (~100 MB).
__launch_bounds__(256)
__global__ void kT(const float* __restrict__ x, bf16* __restrict__ xt,
                   float* __restrict__ sLg){
  __shared__ bf16 XL[64][264];    // 33792 B (264 = 256 + pad, 528B rows, 16-aligned)
  __shared__ float ssqL[256];
  const int t = threadIdx.x;
  const int pb = blockIdx.x*64, b = blockIdx.y;
  const int px = t & 63, cg = t >> 6;
  const float* xb = x + (size_t)b*NC*NPIX + pb + px;
  float ssq = 0.f;
  #pragma unroll
  for (int s4 = 0; s4 < 8; ++s4){
    const float* xp = xb + (size_t)(s4*32 + cg*8)*NPIX;
    alignas(16) bf16 tmp[8];
    #pragma unroll
    for (int j = 0; j < 8; ++j){
      float v = xp[(size_t)j*NPIX];
      ssq += v*v;
      tmp[j] = __float2bfloat16(v);
    }
    *(uint4*)&XL[px][s4*32 + cg*8] = *(const uint4*)tmp;
  }
  ssqL[cg*64 + px] = ssq;
  __syncthreads();
  if (t < 64){
    float tot = ssqL[t] + ssqL[64 + t] + ssqL[128 + t] + ssqL[192 + t];
    sLg[(size_t)b*NPIX + pb + t] = 16.0f / fmaxf(sqrtf(tot), 1e-12f);
  }
  bf16* xr = xt + ((size_t)b*NPIX + pb)*NC;
  const int p = t >> 2, c0 = t & 3;
  #pragma unroll
  for (int k = 0; k < 8; ++k){
    const int c = c0 + k*4;
    *(uint4*)(xr + (size_t)p*NC + c*8) = *(const uint4*)&XL[p][c*8];
  }
}

// ---------------- kA v9: BARRIER-FREE, LDS-FREE GEMM. Both operands load
// global->register (weights wave-private; x^T frags 16B/lane coalesced).
// Norm scale applied post-GEMM via sLg (commutes through GEMM columns).
// Post-phase / Pb,Vb / ctx: verbatim v5. ONE barrier total (before ctx).
__launch_bounds__(256)
__global__ void kA(const bf16* __restrict__ xt, const bf16* __restrict__ wgpack,
                   const float* __restrict__ sLg, float* __restrict__ dout,
                   float* __restrict__ ctxu, float* __restrict__ zacc){
  __shared__ char smem alignas(16) [36864];
  bf16 (*Pb)[72] = (bf16(*)[72])smem;            // [128][72] = 18432
  bf16 (*Vb)[72] = (bf16(*)[72])(smem + 18432);  // [128][72] = 18432
  const int t = threadIdx.x;
  const int pb = blockIdx.x * 64, b = blockIdx.y;
  const int wv = t >> 6, lane = t & 63, m = lane & 15, q4 = lane >> 4;
  const bf16* xrow = xt + ((size_t)b*NPIX + pb)*NC;

  auto wload = [&](int c, int rt)->bf16x8 {  // wave-private frag, lane-identity
    return *(const bf16x8*)(wgpack + ((size_t)(c*24 + wv*6 + rt)*64 + lane)*8);
  };
  auto xload = [&](int s, int pt)->bf16x8 {  // B-frag direct from x^T
    return *(const bf16x8*)(xrow + (size_t)(pt*16 + m)*NC + s*32 + q4*8);
  };

  bf16x8 af[2][6], bfr[2][4];
  #pragma unroll
  for (int rt = 0; rt < 6; ++rt) af[0][rt] = wload(0, rt);
  #pragma unroll
  for (int pt = 0; pt < 4; ++pt) bfr[0][pt] = xload(0, pt);
  #pragma unroll
  for (int rt = 0; rt < 6; ++rt) af[1][rt] = wload(1, rt);
  #pragma unroll
  for (int pt = 0; pt < 4; ++pt) bfr[1][pt] = xload(1, pt);

  floatx4 acc[6][4] = {};
  #pragma unroll
  for (int s = 0; s < 8; ++s){
    const int cur = s & 1;
    #pragma unroll
    for (int rt = 0; rt < 6; ++rt)
      #pragma unroll
      for (int pt = 0; pt < 4; ++pt)
        acc[rt][pt] = __builtin_amdgcn_mfma_f32_16x16x32_bf16(af[cur][rt], bfr[cur][pt], acc[rt][pt], 0, 0, 0);
    if (s < 6){   // prefetch s+2 into the buffer just consumed
      #pragma unroll
      for (int rt = 0; rt < 6; ++rt) af[cur][rt] = wload(s + 2, rt);
      #pragma unroll
      for (int pt = 0; pt < 4; ++pt) bfr[cur][pt] = xload(s + 2, pt);
    }
  }
  // per-px norm factors (precomputed by kT)
  float sv[4];
  #pragma unroll
  for (int pt = 0; pt < 4; ++pt) sv[pt] = sLg[(size_t)b*NPIX + pb + pt*16 + m];
  // ---- post phase: verbatim v5 ----
  #pragma unroll
  for (int pr = 0; pr < 3; ++pr){
    const int ra = 2*pr, rb = 2*pr + 1;
    const int row0 = wv*96 + pr*32;
    const int type = row0 >> 7;          // 0=q, 1=k, 2=v
    if (type == 0){
      const int slice = row0 >> 5;       // head = q k-slice
      const int j0 = (q4 & 1)*4;
      #pragma unroll
      for (int pt = 0; pt < 4; ++pt){
        float va[4], vb[4];
        float mx = -1e30f;
        #pragma unroll
        for (int r = 0; r < 4; ++r){
          va[r] = acc[ra][pt][r]*sv[pt];
          vb[r] = acc[rb][pt][r]*sv[pt];
          mx = fmaxf(mx, fmaxf(va[r], vb[r]));
        }
        mx = fmaxf(mx, __shfl_xor(mx, 16, 64));
        mx = fmaxf(mx, __shfl_xor(mx, 32, 64));
        float se = 0.f;
        #pragma unroll
        for (int r = 0; r < 4; ++r){
          va[r] = __expf(va[r] - mx); vb[r] = __expf(vb[r] - mx);
          se += va[r] + vb[r];
        }
        se += __shfl_xor(se, 16, 64);
        se += __shfl_xor(se, 32, 64);
        const float inv = QSCALE / se;
        alignas(8) bf16 pka[4], pkb[4];
        #pragma unroll
        for (int r = 0; r < 4; ++r){
          pka[r] = __float2bfloat16(va[r]*inv);
          pkb[r] = __float2bfloat16(vb[r]*inv);
        }
        const int ca = (slice*4 + pt)*4 + (q4 >> 1);
        const int cb = ca + 2;
        bf16* pa = (bf16*)(dout + (size_t)(b*NC + ca)*NPIX + pb) + m*8 + j0;
        bf16* pv = (bf16*)(dout + (size_t)(b*NC + cb)*NPIX + pb) + m*8 + j0;
        *(uint2*)pa = *(const uint2*)pka;
        *(uint2*)pv = *(const uint2*)pkb;
      }
    } else if (type == 1){
      const int d0 = row0 - 128;
      float za[4] = {}, zb[4] = {};
      #pragma unroll
      for (int pt = 0; pt < 4; ++pt){
        #pragma unroll
        for (int r = 0; r < 4; ++r){
          float pa = __expf(acc[ra][pt][r]*sv[pt]);
          float pv = __expf(acc[rb][pt][r]*sv[pt]);
          za[r] += pa; zb[r] += pv;
          Pb[d0      + q4*4 + r][pt*16 + m] = __float2bfloat16(pa);
          Pb[d0 + 16 + q4*4 + r][pt*16 + m] = __float2bfloat16(pv);
        }
      }
      #pragma unroll
      for (int r = 0; r < 4; ++r){
        #pragma unroll
        for (int o = 1; o < 16; o <<= 1){
          za[r] += __shfl_xor(za[r], o, 64);
          zb[r] += __shfl_xor(zb[r], o, 64);
        }
      }
      if (m == 0){
        #pragma unroll
        for (int r = 0; r < 4; ++r){
          atomicAdd(&zacc[b*NHID + d0      + q4*4 + r], za[r]);
          atomicAdd(&zacc[b*NHID + d0 + 16 + q4*4 + r], zb[r]);
        }
      }
    } else {
      const int v0 = row0 - 256;
      #pragma unroll
      for (int pt = 0; pt < 4; ++pt)
        #pragma unroll
        for (int r = 0; r < 4; ++r){
          Vb[v0      + q4*4 + r][pt*16 + m] = __float2bfloat16(acc[ra][pt][r]*sv[pt]);
          Vb[v0 + 16 + q4*4 + r][pt*16 + m] = __float2bfloat16(acc[rb][pt][r]*sv[pt]);
        }
    }
  }
  __syncthreads();   // the ONLY barrier: Pb/Vb writes visible
  // ctx MFMA: wave wv = head wv; 64 toks in 2 K-steps (verbatim v5)
  floatx4 cx[2][2] = {};
  #pragma unroll
  for (int k0t = 0; k0t < 64; k0t += 32){
    bf16x8 af2[2], bf2[2];
    #pragma unroll
    for (int dt = 0; dt < 2; ++dt) af2[dt] = *(const bf16x8*)&Pb[wv*32 + dt*16 + m][k0t + q4*8];
    #pragma unroll
    for (int et = 0; et < 2; ++et) bf2[et] = *(const bf16x8*)&Vb[wv*32 + et*16 + m][k0t + q4*8];
    #pragma unroll
    for (int dt = 0; dt < 2; ++dt)
      #pragma unroll
      for (int et = 0; et < 2; ++et)
        cx[dt][et] = __builtin_amdgcn_mfma_f32_16x16x32_bf16(af2[dt], bf2[et], cx[dt][et], 0, 0, 0);
  }
  float* cb2 = ctxu + (size_t)(b*NH + wv)*ND*ND;
  #pragma unroll
  for (int dt = 0; dt < 2; ++dt)
    #pragma unroll
    for (int et = 0; et < 2; ++et)
      #pragma unroll
      for (int r = 0; r < 4; ++r)
        atomicAdd(&cb2[(dt*16 + q4*4 + r)*ND + et*16 + m], cx[dt][et][r]);
}

// ---------------- k4 v2: 64 blocks, LDS-staged, coalesced (unchanged, passed).
__launch_bounds__(256)
__global__ void k4_weff(const float* __restrict__ ctxu, const float* __restrict__ zacc,
                        const float* __restrict__ memkv, const float* __restrict__ wout,
                        bf16* __restrict__ wpack){
  __shared__ float ctxL[4][32][32];        // 16384 B
  __shared__ float woutL[64][129];         // 33024 B
  const int t = threadIdx.x;
  const int o0 = blockIdx.x * 64, b = blockIdx.y;
  {
    const float* ws = wout + (size_t)o0*NHID;
    #pragma unroll
    for (int i = 0; i < 32; ++i){
      const int idx = i*256 + t;
      woutL[idx >> 7][idx & 127] = ws[idx];
    }
  }
  if (t < 128){
    const int h = t >> 5;
    const float* mk = memkv + t*NMEM;
    float me[4]; float z = zacc[b*NHID + t];
    #pragma unroll
    for (int j = 0; j < 4; ++j){ me[j] = __expf(mk[j]); z += me[j]; }
    const float invz = 1.0f / z;
    const float* cp = ctxu + (size_t)(b*NH*ND + t)*ND;
    const float* mv = memkv + (size_t)(NHID + h*ND)*NMEM;
    #pragma unroll
    for (int e = 0; e < ND; ++e){
      float ce = cp[e];
      #pragma unroll
      for (int j = 0; j < 4; ++j) ce += me[j]*mv[e*NMEM + j];
      ctxL[h][t & 31][e] = ce * invz;
    }
  }
  __syncthreads();
  const int ol = t & 63, g = t >> 6;
  float out[32] = {};
  #pragma unroll
  for (int e = 0; e < 32; ++e){
    const float we = woutL[ol][g*32 + e];
    #pragma unroll
    for (int d = 0; d < 32; ++d) out[d] += ctxL[g][d][e] * we;
  }
  const int o = o0 + ol, tile = o >> 4, m16 = o & 15;
  #pragma unroll
  for (int q4k = 0; q4k < 4; ++q4k){
    alignas(16) bf16 tmp[8];
    #pragma unroll
    for (int j = 0; j < 8; ++j) tmp[j] = __float2bfloat16(out[q4k*8 + j]);
    *(uint4*)(wpack + ((size_t)((b*4 + g)*16 + tile)*64 + q4k*16 + m16)*8) = *(const uint4*)tmp;
  }
}

// ---------------- K5 v6: register-direct, load-after-use dbuf (unchanged, passed).
__launch_bounds__(256)
__global__ void k5_out(float* dout, const bf16* __restrict__ wpack,
                       const float* __restrict__ bout, const float* __restrict__ gout){
  __shared__ float red[256];
  __shared__ float nf[64];
  const int t = threadIdx.x;
  const int pb = blockIdx.x * 64, b = blockIdx.y;
  const int wv = t >> 6, lane = t & 63, m = lane & 15, q4 = lane >> 4;
  bf16x8 wf[2][4], qf[2][4];
  auto loadw = [&](int s, bf16x8* dst){
    #pragma unroll
    for (int rt = 0; rt < 4; ++rt)
      dst[rt] = *(const bf16x8*)(wpack + ((size_t)((b*4 + s)*16 + wv*4 + rt)*64 + lane)*8);
  };
  auto loadq = [&](int s, bf16x8* dst){
    #pragma unroll
    for (int pt = 0; pt < 4; ++pt)
      dst[pt] = *(const bf16x8*)((const char*)(dout + (size_t)(b*NC + (s*4 + pt)*4 + q4)*NPIX + pb) + m*16);
  };
  loadw(0, wf[0]); loadq(0, qf[0]);
  loadw(1, wf[1]); loadq(1, qf[1]);
  floatx4 acc[4][4] = {};
  #pragma unroll
  for (int s = 0; s < 4; ++s){
    const int buf = s & 1;
    #pragma unroll
    for (int rt = 0; rt < 4; ++rt)
      #pragma unroll
      for (int pt = 0; pt < 4; ++pt)
        acc[rt][pt] = __builtin_amdgcn_mfma_f32_16x16x32_bf16(wf[buf][rt], qf[buf][pt], acc[rt][pt], 0, 0, 0);
    if (s < 2){ loadw(s + 2, wf[buf]); loadq(s + 2, qf[buf]); }  // after reg reads
  }
  // bias + ssq partials
  float ps[4] = {0.f, 0.f, 0.f, 0.f};
  #pragma unroll
  for (int rt = 0; rt < 4; ++rt){
    const int row = wv*64 + rt*16 + q4*4;
    #pragma unroll
    for (int r = 0; r < 4; ++r){
      const float bias = bout[row + r];
      #pragma unroll
      for (int pt = 0; pt < 4; ++pt){
        acc[rt][pt][r] += bias;
        ps[pt] += acc[rt][pt][r]*acc[rt][pt][r];
      }
    }
  }
  #pragma unroll
  for (int pt = 0; pt < 4; ++pt){
    ps[pt] += __shfl_xor(ps[pt], 16, 64);
    ps[pt] += __shfl_xor(ps[pt], 32, 64);
  }
  if (q4 == 0){
    #pragma unroll
    for (int pt = 0; pt < 4; ++pt) red[wv*64 + pt*16 + m] = ps[pt];
  }
  __syncthreads();
  if (t < 64){
    float tot = red[t] + red[64 + t] + red[128 + t] + red[192 + t];
    nf[t] = 16.0f / fmaxf(sqrtf(tot), 1e-12f);
  }
  __syncthreads();
  float nv[4];
  #pragma unroll
  for (int pt = 0; pt < 4; ++pt) nv[pt] = nf[pt*16 + m];
  #pragma unroll
  for (int rt = 0; rt < 4; ++rt){
    const int row = wv*64 + rt*16 + q4*4;
    #pragma unroll
    for (int r = 0; r < 4; ++r){
      const float gg = gout[row + r];
      float* op = dout + (size_t)(b*NC + row + r)*NPIX + pb + m;
      #pragma unroll
      for (int pt = 0; pt < 4; ++pt)
        op[pt*16] = acc[rt][pt][r]*nv[pt]*gg;
    }
  }
}

extern "C" void kernel_launch(void* const* d_in, const int* in_sizes, int n_in,
                              void* d_out, int out_size, void* d_ws, size_t ws_size,
                              hipStream_t stream) {
  (void)in_sizes; (void)n_in; (void)out_size; (void)ws_size;
  const float* x     = (const float*)d_in[0];
  const float* ng    = (const float*)d_in[1];
  const float* wqkv  = (const float*)d_in[2];
  const float* memkv = (const float*)d_in[3];
  const float* wout  = (const float*)d_in[4];
  const float* bout  = (const float*)d_in[5];
  const float* gout  = (const float*)d_in[6];
  float* dout = (float*)d_out;
  char* ws = (char*)d_ws;
  // workspace layout — total ~35.3 MB
  bf16*  wgpack = (bf16*)(ws);              // 196,608
  bf16*  wpack  = (bf16*)(ws + 196608);     // 1,048,576 -> 1,245,184
  float* ctxu   = (float*)(ws + 1245184);   // 262,144   -> 1,507,328
  float* zacc   = (float*)(ws + 1507328);   // 8,192     -> 1,515,520 (adjacent to ctxu for kW zero)
  float* sLg    = (float*)(ws + 1515520);   // 16*4096*4 = 262,144 -> 1,777,664
  bf16*  xt     = (bf16*)(ws + 1777664);    // 16*4096*256*2 = 33,554,432 -> 35,332,096

  kW     <<<dim3(48),      256, 0, stream>>>(wqkv, ng, wgpack, ctxu);  // zeroes ctxu+zacc
  kT     <<<dim3(64, 16),  256, 0, stream>>>(x, xt, sLg);
  kA     <<<dim3(64, 16),  256, 0, stream>>>(xt, wgpack, sLg, dout, ctxu, zacc);
  k4_weff<<<dim3(4, 16),   256, 0, stream>>>(ctxu, zacc, memkv, wout, wpack);
  k5_out <<<dim3(64, 16),  256, 0, stream>>>(dout, wpack, bout, gout);
}

// Round 13
// 199.083 us; speedup vs baseline: 1.0068x; 1.0068x over previous
//
#include <hip/hip_runtime.h>
#include <hip/hip_bf16.h>

typedef __hip_bfloat16 bf16;
typedef __attribute__((ext_vector_type(8))) short bf16x8;
typedef __attribute__((ext_vector_type(4))) float floatx4;

#define NB 16
#define NC 256
#define NPIX 4096
#define NHID 128
#define NH 4
#define ND 32
#define NMEM 4
#define QSCALE 0.17677669529663687f  // 32^-0.5

// ---------------- kW: pack wqkv*g -> bf16 in MFMA A-frag tile order.
// Also zeroes the ctxu/zacc accumulators (adjacent in ws).
__launch_bounds__(256)
__global__ void kW(const float* __restrict__ wqkv, const float* __restrict__ g,
                   bf16* __restrict__ wgpack, float* __restrict__ zbase){
  const int u = blockIdx.x*256 + threadIdx.x;     // 12288 chunks
  for (int z = u; z < 65536 + 2048; z += 48*256) zbase[z] = 0.f;
  const int s = u / 1536;
  const int r = u - s*1536;
  const int tile = r >> 6, l = r & 63;
  const int row = tile*16 + (l & 15);
  const int kb  = s*32 + (l >> 4)*8;
  const float* wp = wqkv + (size_t)row*NC + kb;
  floatx4 w0 = *(const floatx4*)wp;
  floatx4 w1 = *(const floatx4*)(wp + 4);
  floatx4 g0 = *(const floatx4*)(g + kb);
  floatx4 g1 = *(const floatx4*)(g + kb + 4);
  alignas(16) bf16 tmp[8];
  #pragma unroll
  for (int i = 0; i < 4; ++i){
    tmp[i]   = __float2bfloat16(w0[i]*g0[i]);
    tmp[4+i] = __float2bfloat16(w1[i]*g1[i]);
  }
  *(uint4*)(wgpack + (size_t)u*8) = *(const uint4*)tmp;
}

// ---------------- kA v10: low-register x barrier-free (the untested cell).
// 512 thr / 8 waves = 4 row-groups x 2 px-halves; acc[6][2]=48 AGPR -> ~110
// unified regs -> 4 waves/SIMD = 16 waves/CU (2x every 4-wave variant).
// GEMM: ZERO barriers, ZERO LDS. B-frag needs no cross-lane transpose: each
// lane's 8 channels gathered directly from f32 x + cvt. ssq kept per-pixel
// in registers, reduced via shfl (no sL LDS). Post/ctx: verbatim v2 (passed).
__launch_bounds__(512, 4)
__global__ void kA(const float* __restrict__ x, const bf16* __restrict__ wgpack,
                   float* __restrict__ dout,
                   float* __restrict__ ctxu, float* __restrict__ zacc){
  __shared__ char smem alignas(16) [36864];
  bf16 (*Pb)[72] = (bf16(*)[72])smem;            // [128][72] = 18432
  bf16 (*Vb)[72] = (bf16(*)[72])(smem + 18432);  // [128][72] = 18432
  float* cxL = (float*)smem;                     // [4][32][32] alias Pb (post-ctx)
  const int t = threadIdx.x;
  const int pb = blockIdx.x * 64, b = blockIdx.y;
  const int wv = t >> 6, lane = t & 63, m = lane & 15, q4 = lane >> 4;
  const int rg = wv & 3, ph = wv >> 2;
  const float* xb = x + (size_t)b*NC*NPIX + pb;

  float ssqv[2] = {0.f, 0.f};
  floatx4 acc[6][2] = {};
  bf16x8 af[6];
  #pragma unroll
  for (int rt = 0; rt < 6; ++rt)
    af[rt] = *(const bf16x8*)(wgpack + ((size_t)(rg*6 + rt)*64 + lane)*8);
  #pragma unroll
  for (int s = 0; s < 8; ++s){
    // gather x fragments: per-lane 8 channels (j) x 2 pixels (pt), f32 direct
    float xf[2][8];
    #pragma unroll
    for (int pt = 0; pt < 2; ++pt){
      const float* xp = xb + (size_t)(s*32 + q4*8)*NPIX + (ph*2 + pt)*16 + m;
      #pragma unroll
      for (int j = 0; j < 8; ++j) xf[pt][j] = xp[(size_t)j*NPIX];
    }
    bf16x8 bfr[2];
    #pragma unroll
    for (int pt = 0; pt < 2; ++pt){
      alignas(16) bf16 tmp[8];
      #pragma unroll
      for (int j = 0; j < 8; ++j){
        ssqv[pt] += xf[pt][j]*xf[pt][j];
        tmp[j] = __float2bfloat16(xf[pt][j]);
      }
      bfr[pt] = *(const bf16x8*)tmp;
    }
    #pragma unroll
    for (int rt = 0; rt < 6; ++rt)
      #pragma unroll
      for (int pt = 0; pt < 2; ++pt)
        acc[rt][pt] = __builtin_amdgcn_mfma_f32_16x16x32_bf16(af[rt], bfr[pt], acc[rt][pt], 0, 0, 0);
    if (s < 7){   // next step's weight frags (L2-hot, wave-private)
      #pragma unroll
      for (int rt = 0; rt < 6; ++rt)
        af[rt] = *(const bf16x8*)(wgpack + ((size_t)((s+1)*24 + rg*6 + rt)*64 + lane)*8);
    }
  }
  // per-pixel norm: full 256-ch sum = own 64 ch + shuffle across q4 groups
  float sv[2];
  #pragma unroll
  for (int pt = 0; pt < 2; ++pt){
    float tot = ssqv[pt];
    tot += __shfl_xor(tot, 16, 64);
    tot += __shfl_xor(tot, 32, 64);
    sv[pt] = 16.0f / fmaxf(sqrtf(tot), 1e-12f);
  }
  // ---- post phase (verbatim v2, rows rg*96..+96, px half ph) ----
  #pragma unroll
  for (int pr = 0; pr < 3; ++pr){
    const int ra = 2*pr, rb = 2*pr + 1;
    const int row0 = rg*96 + pr*32;
    const int type = row0 >> 7;          // 0=q, 1=k, 2=v
    if (type == 0){
      const int slice = row0 >> 5;       // head = q k-slice
      const int j0 = (q4 & 1)*4;
      #pragma unroll
      for (int pt = 0; pt < 2; ++pt){
        const int gpt = ph*2 + pt;
        float va[4], vb4[4];
        float mx = -1e30f;
        #pragma unroll
        for (int r = 0; r < 4; ++r){
          va[r]  = acc[ra][pt][r]*sv[pt];
          vb4[r] = acc[rb][pt][r]*sv[pt];
          mx = fmaxf(mx, fmaxf(va[r], vb4[r]));
        }
        mx = fmaxf(mx, __shfl_xor(mx, 16, 64));
        mx = fmaxf(mx, __shfl_xor(mx, 32, 64));
        float se = 0.f;
        #pragma unroll
        for (int r = 0; r < 4; ++r){
          va[r] = __expf(va[r] - mx); vb4[r] = __expf(vb4[r] - mx);
          se += va[r] + vb4[r];
        }
        se += __shfl_xor(se, 16, 64);
        se += __shfl_xor(se, 32, 64);
        const float inv = QSCALE / se;
        alignas(8) bf16 pka[4], pkb[4];
        #pragma unroll
        for (int r = 0; r < 4; ++r){
          pka[r] = __float2bfloat16(va[r]*inv);
          pkb[r] = __float2bfloat16(vb4[r]*inv);
        }
        const int ca = (slice*4 + gpt)*4 + (q4 >> 1);
        const int cb = ca + 2;
        bf16* pa = (bf16*)(dout + (size_t)(b*NC + ca)*NPIX + pb) + m*8 + j0;
        bf16* pv = (bf16*)(dout + (size_t)(b*NC + cb)*NPIX + pb) + m*8 + j0;
        *(uint2*)pa = *(const uint2*)pka;
        *(uint2*)pv = *(const uint2*)pkb;
      }
    } else if (type == 1){
      const int d0 = row0 - 128;
      float za[4] = {}, zb[4] = {};
      #pragma unroll
      for (int pt = 0; pt < 2; ++pt){
        const int gpt = ph*2 + pt;
        #pragma unroll
        for (int r = 0; r < 4; ++r){
          float pa = __expf(acc[ra][pt][r]*sv[pt]);
          float pv = __expf(acc[rb][pt][r]*sv[pt]);
          za[r] += pa; zb[r] += pv;
          Pb[d0      + q4*4 + r][gpt*16 + m] = __float2bfloat16(pa);
          Pb[d0 + 16 + q4*4 + r][gpt*16 + m] = __float2bfloat16(pv);
        }
      }
      #pragma unroll
      for (int r = 0; r < 4; ++r){
        #pragma unroll
        for (int o = 1; o < 16; o <<= 1){
          za[r] += __shfl_xor(za[r], o, 64);
          zb[r] += __shfl_xor(zb[r], o, 64);
        }
      }
      if (m == 0){
        #pragma unroll
        for (int r = 0; r < 4; ++r){
          atomicAdd(&zacc[b*NHID + d0      + q4*4 + r], za[r]);
          atomicAdd(&zacc[b*NHID + d0 + 16 + q4*4 + r], zb[r]);
        }
      }
    } else {
      const int v0 = row0 - 256;
      #pragma unroll
      for (int pt = 0; pt < 2; ++pt){
        const int gpt = ph*2 + pt;
        #pragma unroll
        for (int r = 0; r < 4; ++r){
          Vb[v0      + q4*4 + r][gpt*16 + m] = __float2bfloat16(acc[ra][pt][r]*sv[pt]);
          Vb[v0 + 16 + q4*4 + r][gpt*16 + m] = __float2bfloat16(acc[rb][pt][r]*sv[pt]);
        }
      }
    }
  }
  __syncthreads();   // Pb/Vb visible
  // ctx MFMA: wave = (head rg, token-half ph); one 32-tok K-step each
  floatx4 cx[2][2] = {};
  {
    const int k0t = ph*32;
    bf16x8 paf[2], pvf[2];
    #pragma unroll
    for (int dt = 0; dt < 2; ++dt) paf[dt] = *(const bf16x8*)&Pb[rg*32 + dt*16 + m][k0t + q4*8];
    #pragma unroll
    for (int et = 0; et < 2; ++et) pvf[et] = *(const bf16x8*)&Vb[rg*32 + et*16 + m][k0t + q4*8];
    #pragma unroll
    for (int dt = 0; dt < 2; ++dt)
      #pragma unroll
      for (int et = 0; et < 2; ++et)
        cx[dt][et] = __builtin_amdgcn_mfma_f32_16x16x32_bf16(paf[dt], pvf[et], cx[dt][et], 0, 0, 0);
  }
  __syncthreads();   // Pb/Vb reads complete -> cxL (alias) writable
  if (ph == 1){      // token-half 1 parks partial in LDS (halves global atomics)
    #pragma unroll
    for (int dt = 0; dt < 2; ++dt)
      #pragma unroll
      for (int et = 0; et < 2; ++et)
        #pragma unroll
        for (int r = 0; r < 4; ++r)
          cxL[rg*1024 + (dt*16 + q4*4 + r)*32 + et*16 + m] = cx[dt][et][r];
  }
  __syncthreads();
  if (ph == 0){
    float* cb2 = ctxu + (size_t)(b*NH + rg)*ND*ND;
    #pragma unroll
    for (int dt = 0; dt < 2; ++dt)
      #pragma unroll
      for (int et = 0; et < 2; ++et)
        #pragma unroll
        for (int r = 0; r < 4; ++r)
          atomicAdd(&cb2[(dt*16 + q4*4 + r)*ND + et*16 + m],
                    cx[dt][et][r] + cxL[rg*1024 + (dt*16 + q4*4 + r)*32 + et*16 + m]);
  }
}

// ---------------- k4 v2: 64 blocks, LDS-staged, coalesced (unchanged, passed).
__launch_bounds__(256)
__global__ void k4_weff(const float* __restrict__ ctxu, const float* __restrict__ zacc,
                        const float* __restrict__ memkv, const float* __restrict__ wout,
                        bf16* __restrict__ wpack){
  __shared__ float ctxL[4][32][32];        // 16384 B
  __shared__ float woutL[64][129];         // 33024 B
  const int t = threadIdx.x;
  const int o0 = blockIdx.x * 64, b = blockIdx.y;
  {
    const float* ws = wout + (size_t)o0*NHID;
    #pragma unroll
    for (int i = 0; i < 32; ++i){
      const int idx = i*256 + t;
      woutL[idx >> 7][idx & 127] = ws[idx];
    }
  }
  if (t < 128){
    const int h = t >> 5;
    const float* mk = memkv + t*NMEM;
    float me[4]; float z = zacc[b*NHID + t];
    #pragma unroll
    for (int j = 0; j < 4; ++j){ me[j] = __expf(mk[j]); z += me[j]; }
    const float invz = 1.0f / z;
    const float* cp = ctxu + (size_t)(b*NH*ND + t)*ND;
    const float* mv = memkv + (size_t)(NHID + h*ND)*NMEM;
    #pragma unroll
    for (int e = 0; e < ND; ++e){
      float ce = cp[e];
      #pragma unroll
      for (int j = 0; j < 4; ++j) ce += me[j]*mv[e*NMEM + j];
      ctxL[h][t & 31][e] = ce * invz;
    }
  }
  __syncthreads();
  const int ol = t & 63, g = t >> 6;
  float out[32] = {};
  #pragma unroll
  for (int e = 0; e < 32; ++e){
    const float we = woutL[ol][g*32 + e];
    #pragma unroll
    for (int d = 0; d < 32; ++d) out[d] += ctxL[g][d][e] * we;
  }
  const int o = o0 + ol, tile = o >> 4, m16 = o & 15;
  #pragma unroll
  for (int q4k = 0; q4k < 4; ++q4k){
    alignas(16) bf16 tmp[8];
    #pragma unroll
    for (int j = 0; j < 8; ++j) tmp[j] = __float2bfloat16(out[q4k*8 + j]);
    *(uint4*)(wpack + ((size_t)((b*4 + g)*16 + tile)*64 + q4k*16 + m16)*8) = *(const uint4*)tmp;
  }
}

// ---------------- K5 v6: register-direct, load-after-use dbuf (unchanged, passed).
__launch_bounds__(256)
__global__ void k5_out(float* dout, const bf16* __restrict__ wpack,
                       const float* __restrict__ bout, const float* __restrict__ gout){
  __shared__ float red[256];
  __shared__ float nf[64];
  const int t = threadIdx.x;
  const int pb = blockIdx.x * 64, b = blockIdx.y;
  const int wv = t >> 6, lane = t & 63, m = lane & 15, q4 = lane >> 4;
  bf16x8 wf[2][4], qf[2][4];
  auto loadw = [&](int s, bf16x8* dst){
    #pragma unroll
    for (int rt = 0; rt < 4; ++rt)
      dst[rt] = *(const bf16x8*)(wpack + ((size_t)((b*4 + s)*16 + wv*4 + rt)*64 + lane)*8);
  };
  auto loadq = [&](int s, bf16x8* dst){
    #pragma unroll
    for (int pt = 0; pt < 4; ++pt)
      dst[pt] = *(const bf16x8*)((const char*)(dout + (size_t)(b*NC + (s*4 + pt)*4 + q4)*NPIX + pb) + m*16);
  };
  loadw(0, wf[0]); loadq(0, qf[0]);
  loadw(1, wf[1]); loadq(1, qf[1]);
  floatx4 acc[4][4] = {};
  #pragma unroll
  for (int s = 0; s < 4; ++s){
    const int buf = s & 1;
    #pragma unroll
    for (int rt = 0; rt < 4; ++rt)
      #pragma unroll
      for (int pt = 0; pt < 4; ++pt)
        acc[rt][pt] = __builtin_amdgcn_mfma_f32_16x16x32_bf16(wf[buf][rt], qf[buf][pt], acc[rt][pt], 0, 0, 0);
    if (s < 2){ loadw(s + 2, wf[buf]); loadq(s + 2, qf[buf]); }  // after reg reads
  }
  // bias + ssq partials
  float ps[4] = {0.f, 0.f, 0.f, 0.f};
  #pragma unroll
  for (int rt = 0; rt < 4; ++rt){
    const int row = wv*64 + rt*16 + q4*4;
    #pragma unroll
    for (int r = 0; r < 4; ++r){
      const float bias = bout[row + r];
      #pragma unroll
      for (int pt = 0; pt < 4; ++pt){
        acc[rt][pt][r] += bias;
        ps[pt] += acc[rt][pt][r]*acc[rt][pt][r];
      }
    }
  }
  #pragma unroll
  for (int pt = 0; pt < 4; ++pt){
    ps[pt] += __shfl_xor(ps[pt], 16, 64);
    ps[pt] += __shfl_xor(ps[pt], 32, 64);
  }
  if (q4 == 0){
    #pragma unroll
    for (int pt = 0; pt < 4; ++pt) red[wv*64 + pt*16 + m] = ps[pt];
  }
  __syncthreads();
  if (t < 64){
    float tot = red[t] + red[64 + t] + red[128 + t] + red[192 + t];
    nf[t] = 16.0f / fmaxf(sqrtf(tot), 1e-12f);
  }
  __syncthreads();
  float nv[4];
  #pragma unroll
  for (int pt = 0; pt < 4; ++pt) nv[pt] = nf[pt*16 + m];
  #pragma unroll
  for (int rt = 0; rt < 4; ++rt){
    const int row = wv*64 + rt*16 + q4*4;
    #pragma unroll
    for (int r = 0; r < 4; ++r){
      const float gg = gout[row + r];
      float* op = dout + (size_t)(b*NC + row + r)*NPIX + pb + m;
      #pragma unroll
      for (int pt = 0; pt < 4; ++pt)
        op[pt*16] = acc[rt][pt][r]*nv[pt]*gg;
    }
  }
}

extern "C" void kernel_launch(void* const* d_in, const int* in_sizes, int n_in,
                              void* d_out, int out_size, void* d_ws, size_t ws_size,
                              hipStream_t stream) {
  (void)in_sizes; (void)n_in; (void)out_size; (void)ws_size;
  const float* x     = (const float*)d_in[0];
  const float* ng    = (const float*)d_in[1];
  const float* wqkv  = (const float*)d_in[2];
  const float* memkv = (const float*)d_in[3];
  const float* wout  = (const float*)d_in[4];
  const float* bout  = (const float*)d_in[5];
  const float* gout  = (const float*)d_in[6];
  float* dout = (float*)d_out;
  char* ws = (char*)d_ws;
  // workspace layout — total 1,515,520 B (~1.45 MB)
  bf16*  wgpack = (bf16*)(ws);              // 8*24*64*8*2  = 196608
  bf16*  wpack  = (bf16*)(ws + 196608);     // 16*4*16*64*8*2 = 1048576
  float* ctxu   = (float*)(ws + 1245184);   // 16*4*32*32*4 = 262144
  float* zacc   = (float*)(ws + 1507328);   // 16*128*4     = 8192

  kW     <<<dim3(48),      256, 0, stream>>>(wqkv, ng, wgpack, ctxu);  // zeroes ctxu+zacc
  kA     <<<dim3(64, 16),  512, 0, stream>>>(x, wgpack, dout, ctxu, zacc);
  k4_weff<<<dim3(4, 16),   256, 0, stream>>>(ctxu, zacc, memkv, wout, wpack);
  k5_out <<<dim3(64, 16),  256, 0, stream>>>(dout, wpack, bout, gout);
}